// Round 6
// baseline (1526.651 us; speedup 1.0000x reference)
//
#include <hip/hip_runtime.h>

// 8-layer transformer LM forward. V=128, E=512, L=8, H=8, B=4, T=1024.
// Round 6: swizzled+prefetched GEMM (BM=128/BN=64/BK=64, VGPR staging);
// V transposed once per (bh,kt) into global vt_g (vprep, also does tile sums);
// attn: coalesced K/Vt staging + register prefetch + deferred lrow reduction.

#define V_  128
#define E_  512
#define L_  8
#define H_  8
#define B_  4
#define T_  1024
#define N_  (B_*T_)    // 4096 tokens
#define DH_ 64
#define E3_ 1536

typedef __attribute__((ext_vector_type(8))) short   bf16x8;   // MFMA A/B frag
typedef __attribute__((ext_vector_type(4))) float   floatx4;  // MFMA C/D frag

// swizzled LDS offset (ushort units): 64-wide rows, 8-elem blocks XORed by row&7
#define SW(row,k8) (((row) << 6) + ((((k8) ^ ((row) & 7))) << 3))

__device__ __forceinline__ unsigned short f2bf(float f) {
    union { float f; unsigned int i; } v; v.f = f;
    unsigned int x = v.i;
    return (unsigned short)((x + 0x7fffu + ((x >> 16) & 1u)) >> 16);  // RNE
}
__device__ __forceinline__ float bf2f(unsigned short u) {
    union { unsigned int i; float f; } v; v.i = ((unsigned int)u) << 16; return v.f;
}

// ---------------- single-dispatch fp32 -> bf16 weight convert ----------------
#define CVT_N0 6291456   // qkv  L*1536*512
#define CVT_N1 2097152   // per-square L*512*512
#define CVT_TOT (CVT_N0 + 4*CVT_N1 + V_*E_)
__global__ void cvt_all_kernel(const float* __restrict__ s0, const float* __restrict__ s1,
                               const float* __restrict__ s2, const float* __restrict__ s3,
                               const float* __restrict__ s4, const float* __restrict__ s5,
                               unsigned short* __restrict__ dst) {
    long i = (long)(blockIdx.x * blockDim.x + threadIdx.x) * 4;
    if (i >= CVT_TOT) return;
    const float* src; long off;
    if      (i < CVT_N0)               { src = s0; off = i; }
    else if (i < CVT_N0 + CVT_N1)      { src = s1; off = i - CVT_N0; }
    else if (i < CVT_N0 + 2*CVT_N1)    { src = s2; off = i - CVT_N0 - CVT_N1; }
    else if (i < CVT_N0 + 3*CVT_N1)    { src = s3; off = i - CVT_N0 - 2L*CVT_N1; }
    else if (i < CVT_N0 + 4*CVT_N1)    { src = s4; off = i - CVT_N0 - 3L*CVT_N1; }
    else                               { src = s5; off = i - CVT_N0 - 4L*CVT_N1; }
    float4 v = *(const float4*)(src + off);
    ushort4 o; o.x = f2bf(v.x); o.y = f2bf(v.y); o.z = f2bf(v.z); o.w = f2bf(v.w);
    *(ushort4*)(dst + i) = o;
}

// ---------------- embedding: write fp32 + bf16 ----------------
__global__ void embed_kernel(const int* __restrict__ tok, const float* __restrict__ emb,
                             float* __restrict__ xf, unsigned short* __restrict__ xb) {
    int idx = blockIdx.x * blockDim.x + threadIdx.x;
    if (idx >= N_ * E_) return;
    int n = idx >> 9;
    int e = idx & (E_ - 1);
    float v = emb[tok[n] * E_ + e];
    xf[idx] = v; xb[idx] = f2bf(v);
}

// ---------------- MFMA GEMM: BM=128, BN=64, BK=64; swizzled; reg prefetch ----------------
__device__ __forceinline__ void gemm_ldchunk(
    const unsigned short* __restrict__ A, const unsigned short* __restrict__ W,
    int m0, int n0, int K, int k0, int tid, uint4 areg[4], uint4 breg[2])
{
    int k8 = (tid & 7) * 8, rb = tid >> 3;
    #pragma unroll
    for (int c = 0; c < 4; ++c)
        areg[c] = *(const uint4*)(A + (size_t)(m0 + rb + 32 * c) * K + k0 + k8);
    #pragma unroll
    for (int c = 0; c < 2; ++c)
        breg[c] = *(const uint4*)(W + (size_t)(n0 + rb + 32 * c) * K + k0 + k8);
}

template<int RELU, int WF, int WB>
__global__ __launch_bounds__(256) void gemm_mfma(
    const unsigned short* __restrict__ A, const unsigned short* __restrict__ W,
    const float* __restrict__ bias, float* __restrict__ Cf, unsigned short* __restrict__ Cb,
    int M, int Nout, int K)
{
    __shared__ unsigned short Asm[128 * 64];   // 16 KB, swizzled
    __shared__ unsigned short Bsm[64 * 64];    //  8 KB, swizzled
    int tid = threadIdx.x;
    int wv = tid >> 6, ln = tid & 63;
    int lquad = ln >> 4, lmod = ln & 15;
    int m0 = blockIdx.y * 128, n0 = blockIdx.x * 64;
    int rb = tid >> 3, k8l = tid & 7;

    floatx4 acc[2][4] = {};
    uint4 areg[4], breg[2];
    gemm_ldchunk(A, W, m0, n0, K, 0, tid, areg, breg);

    for (int k0 = 0; k0 < K; k0 += 64) {
        __syncthreads();                     // prev chunk's readers done
        #pragma unroll
        for (int c = 0; c < 4; ++c)
            *(uint4*)&Asm[SW(rb + 32 * c, k8l)] = areg[c];
        #pragma unroll
        for (int c = 0; c < 2; ++c)
            *(uint4*)&Bsm[SW(rb + 32 * c, k8l)] = breg[c];
        if (k0 + 64 < K)
            gemm_ldchunk(A, W, m0, n0, K, k0 + 64, tid, areg, breg);  // overlap w/ MFMA
        __syncthreads();                     // staged
        #pragma unroll
        for (int ks = 0; ks < 2; ++ks) {
            bf16x8 af[2], bfr[4];
            #pragma unroll
            for (int i = 0; i < 2; ++i)
                af[i] = *(const bf16x8*)&Asm[SW(32 * wv + 16 * i + lmod, ks * 4 + lquad)];
            #pragma unroll
            for (int j = 0; j < 4; ++j)
                bfr[j] = *(const bf16x8*)&Bsm[SW(16 * j + lmod, ks * 4 + lquad)];
            #pragma unroll
            for (int i = 0; i < 2; ++i)
                #pragma unroll
                for (int j = 0; j < 4; ++j)
                    acc[i][j] = __builtin_amdgcn_mfma_f32_16x16x32_bf16(af[i], bfr[j], acc[i][j], 0, 0, 0);
        }
    }
    #pragma unroll
    for (int i = 0; i < 2; ++i)
        #pragma unroll
        for (int j = 0; j < 4; ++j) {
            int n = n0 + 16 * j + lmod;
            float bj = bias[n];
            #pragma unroll
            for (int v = 0; v < 4; ++v) {
                int m = m0 + 32 * wv + 16 * i + 4 * lquad + v;
                float val = acc[i][j][v] + bj;
                if (RELU) val = fmaxf(val, 0.f);
                if (WF) Cf[(size_t)m * Nout + n] = val;
                if (WB) Cb[(size_t)m * Nout + n] = f2bf(val);
            }
        }
}

// ---------------- vprep: V transpose -> vt_g[bh][d][k] + tile sums ----------------
// Grid (32 bh, 16 kt), 256 thr. Coalesced 128B row reads; one transpose per tile.
__global__ __launch_bounds__(256) void vprep_kernel(const unsigned short* __restrict__ qkv,
                                                    unsigned short* __restrict__ vt_g,
                                                    float* __restrict__ vtile) {
    int bh = blockIdx.x, kt = blockIdx.y;
    int b = bh >> 3, h = bh & 7;
    int tid = threadIdx.x, wv = tid >> 6, ln = tid & 63;
    int k0 = kt * 64;
    size_t base = (size_t)b * T_ * E3_ + h * 192 + 128;

    // lane = d; wave wv covers k rows k0+16wv .. +16 (each read = 128B coalesced row)
    unsigned short vals[16];
    float s = 0.f;
    #pragma unroll
    for (int i = 0; i < 16; ++i) {
        vals[i] = qkv[base + (size_t)(k0 + wv * 16 + i) * E3_ + ln];
        s += bf2f(vals[i]);
    }
    // write transposed: row d=ln, k contiguous
    #pragma unroll
    for (int hf = 0; hf < 2; ++hf) {
        union { unsigned short u[8]; uint4 v; } pk;
        #pragma unroll
        for (int i = 0; i < 8; ++i) pk.u[i] = vals[hf * 8 + i];
        *(uint4*)&vt_g[((size_t)(bh * 64 + ln)) * T_ + k0 + wv * 16 + hf * 8] = pk.v;
    }
    __shared__ float part[4][64];
    part[wv][ln] = s;
    __syncthreads();
    if (tid < 64)
        vtile[((size_t)bh * 16 + kt) * 64 + tid] =
            part[0][tid] + part[1][tid] + part[2][tid] + part[3][tid];
}

// ---------------- MFMA flash attention ----------------
// Grid (32 bh, 16 qt); 256 thr = 4 waves. Masked scores are ZERO (=> p = 1).
__device__ __forceinline__ void attn_ldchunk(
    const unsigned short* __restrict__ qkv, const unsigned short* __restrict__ vt_g,
    size_t base, int bh, int k0, int tid, uint4 kreg[2], uint4 vreg[2])
{
    int rb = tid >> 3, k8 = (tid & 7) * 8;
    #pragma unroll
    for (int c = 0; c < 2; ++c) {
        int r = rb + 32 * c;
        kreg[c] = *(const uint4*)&qkv[base + (size_t)(k0 + r) * E3_ + 64 + k8];
        vreg[c] = *(const uint4*)&vt_g[((size_t)(bh * 64 + r)) * T_ + k0 + k8];
    }
}

__global__ __launch_bounds__(256) void attn_mfma(const unsigned short* __restrict__ qkv,
                                                 const unsigned short* __restrict__ vt_g,
                                                 const float* __restrict__ vtile,
                                                 unsigned short* __restrict__ outb)
{
    __shared__ unsigned short Qs[64 * 64];  // [q][d] swizzled
    __shared__ unsigned short Ks[64 * 64];  // [k][d] swizzled
    __shared__ unsigned short Vs[64 * 64];  // [d][k] swizzled
    __shared__ unsigned short Ps[64 * 64];  // [q][k] swizzled

    int tid = threadIdx.x;
    int wv = tid >> 6, ln = tid & 63;
    int lquad = ln >> 4, lmod = ln & 15;
    int bh = blockIdx.x, qt = blockIdx.y;
    int b = bh >> 3, h = bh & 7;
    int q0 = qt * 64;
    int rb = tid >> 3, k8l = tid & 7;
    const float scale = 0.125f;
    size_t base = (size_t)b * T_ * E3_ + h * 192;

    for (int c = tid; c < 512; c += 256) {
        int r = c >> 3, k8 = c & 7;
        *(uint4*)&Qs[SW(r, k8)] = *(const uint4*)&qkv[base + (size_t)(q0 + r) * E3_ + k8 * 8];
    }

    float lrow[4] = {0.f, 0.f, 0.f, 0.f};
    floatx4 Oa[4] = {};
    uint4 kreg[2], vreg[2];
    attn_ldchunk(qkv, vt_g, base, bh, 0, tid, kreg, vreg);

    for (int kt = 0; kt <= qt; ++kt) {
        int k0 = kt * 64;
        __syncthreads();   // Qs ready (1st) / prior Ks,Vs,Ps readers done
        #pragma unroll
        for (int c = 0; c < 2; ++c) {
            int r = rb + 32 * c;
            *(uint4*)&Ks[SW(r, k8l)] = kreg[c];
            *(uint4*)&Vs[SW(r, k8l)] = vreg[c];
        }
        if (kt < qt)
            attn_ldchunk(qkv, vt_g, base, bh, k0 + 64, tid, kreg, vreg);  // overlap
        __syncthreads();

        // S strip = Q[16 rows]·K^T
        floatx4 sacc[4] = {};
        #pragma unroll
        for (int ks = 0; ks < 2; ++ks) {
            bf16x8 aq = *(const bf16x8*)&Qs[SW(16 * wv + lmod, ks * 4 + lquad)];
            #pragma unroll
            for (int j = 0; j < 4; ++j) {
                bf16x8 bk = *(const bf16x8*)&Ks[SW(16 * j + lmod, ks * 4 + lquad)];
                sacc[j] = __builtin_amdgcn_mfma_f32_16x16x32_bf16(aq, bk, sacc[j], 0, 0, 0);
            }
        }
        // p = exp(s*scale) (masked => exp(0)=1); per-lane partial sums only
        #pragma unroll
        for (int v = 0; v < 4; ++v) {
            int qg = q0 + 16 * wv + 4 * lquad + v;
            int row = 16 * wv + 4 * lquad + v;
            #pragma unroll
            for (int j = 0; j < 4; ++j) {
                int kg = k0 + 16 * j + lmod;
                float p = (kg <= qg) ? __expf(sacc[j][v] * scale) : 1.0f;
                lrow[v] += p;
                int col = 16 * j + lmod;
                Ps[SW(row, col >> 3) + (col & 7)] = f2bf(p);
            }
        }
        __syncthreads();   // Ps ready
        #pragma unroll
        for (int ks = 0; ks < 2; ++ks) {
            bf16x8 ap = *(const bf16x8*)&Ps[SW(16 * wv + lmod, ks * 4 + lquad)];
            #pragma unroll
            for (int f = 0; f < 4; ++f) {
                bf16x8 bv = *(const bf16x8*)&Vs[SW(16 * f + lmod, ks * 4 + lquad)];
                Oa[f] = __builtin_amdgcn_mfma_f32_16x16x32_bf16(ap, bv, Oa[f], 0, 0, 0);
            }
        }
    }

    // deferred row-sum reduction (16-lane groups share a row)
    #pragma unroll
    for (int v = 0; v < 4; ++v)
        #pragma unroll
        for (int msk = 1; msk < 16; msk <<= 1) lrow[v] += __shfl_xor(lrow[v], msk);

    // fully-masked suffix: p = 1 exactly; O += suffix V sums; l += count
    if (qt < 15) {
        float Km = (float)((15 - qt) * 64);
        #pragma unroll
        for (int v = 0; v < 4; ++v) lrow[v] += Km;
        #pragma unroll
        for (int f = 0; f < 4; ++f) {
            float sv = 0.f;
            for (int kt = qt + 1; kt < 16; ++kt)
                sv += vtile[((size_t)bh * 16 + kt) * 64 + 16 * f + lmod];
            #pragma unroll
            for (int v = 0; v < 4; ++v) Oa[f][v] += sv;
        }
    }

    #pragma unroll
    for (int f = 0; f < 4; ++f)
        #pragma unroll
        for (int v = 0; v < 4; ++v) {
            int q = q0 + 16 * wv + 4 * lquad + v;
            outb[(size_t)(b * T_ + q) * E_ + h * DH_ + 16 * f + lmod] = f2bf(Oa[f][v] / lrow[v]);
        }
}

// ---------------- residual add + LN: wave-per-row ----------------
__global__ __launch_bounds__(256) void add_ln_kernel(
    const float* __restrict__ a, const float* __restrict__ r,
    const float* __restrict__ s, const float* __restrict__ bpar,
    float* __restrict__ outF, unsigned short* __restrict__ outB)
{
    int tid = threadIdx.x, wv = tid >> 6, ln = tid & 63;
    int n = blockIdx.x * 4 + wv;
    int e = ln * 8;
    size_t base = (size_t)n * E_ + e;
    float4 a0 = *(const float4*)&a[base],     a1 = *(const float4*)&a[base + 4];
    float4 r0 = *(const float4*)&r[base],     r1 = *(const float4*)&r[base + 4];
    float v[8] = {a0.x + r0.x, a0.y + r0.y, a0.z + r0.z, a0.w + r0.w,
                  a1.x + r1.x, a1.y + r1.y, a1.z + r1.z, a1.w + r1.w};

    float sm = 0.f;
    #pragma unroll
    for (int i = 0; i < 8; ++i) sm += v[i];
    #pragma unroll
    for (int msk = 1; msk < 64; msk <<= 1) sm += __shfl_xor(sm, msk);
    float mu = sm * (1.f / 512.f);

    float ss = 0.f;
    #pragma unroll
    for (int i = 0; i < 8; ++i) { v[i] -= mu; ss += v[i] * v[i]; }
    #pragma unroll
    for (int msk = 1; msk < 64; msk <<= 1) ss += __shfl_xor(ss, msk);
    float rstd = rsqrtf(ss * (1.f / 512.f) + 1e-5f);

    float4 sc0 = *(const float4*)&s[e],    sc1 = *(const float4*)&s[e + 4];
    float4 bp0 = *(const float4*)&bpar[e], bp1 = *(const float4*)&bpar[e + 4];
    float o[8];
    o[0] = v[0] * rstd * sc0.x + bp0.x; o[1] = v[1] * rstd * sc0.y + bp0.y;
    o[2] = v[2] * rstd * sc0.z + bp0.z; o[3] = v[3] * rstd * sc0.w + bp0.w;
    o[4] = v[4] * rstd * sc1.x + bp1.x; o[5] = v[5] * rstd * sc1.y + bp1.y;
    o[6] = v[6] * rstd * sc1.z + bp1.z; o[7] = v[7] * rstd * sc1.w + bp1.w;
    *(float4*)&outF[base]     = make_float4(o[0], o[1], o[2], o[3]);
    *(float4*)&outF[base + 4] = make_float4(o[4], o[5], o[6], o[7]);
    union { unsigned short u[8]; uint4 q; } pk;
    #pragma unroll
    for (int i = 0; i < 8; ++i) pk.u[i] = f2bf(o[i]);
    *(uint4*)&outB[base] = pk.q;
}

// ---------------- per-row loss + fp32 logits out ----------------
__global__ __launch_bounds__(128) void loss_row_kernel(
    const float* __restrict__ logits, const int* __restrict__ tgt,
    float* __restrict__ out_logits, float* __restrict__ rowloss)
{
    int n = blockIdx.x, i = threadIdx.x;
    float x = logits[(size_t)n * V_ + i];
    out_logits[(size_t)n * V_ + i] = x;

    __shared__ float redA[2], redB[2];
    __shared__ float xt;
    int lane = i & 63, w = i >> 6;
    if (i == tgt[n]) xt = x;

    float m = x;
    #pragma unroll
    for (int off = 32; off; off >>= 1) m = fmaxf(m, __shfl_down(m, off, 64));
    if (lane == 0) redA[w] = m;
    __syncthreads();
    m = fmaxf(redA[0], redA[1]);
    __syncthreads();

    float ev = __expf(x - m);
    float se = ev, sx = x;
    #pragma unroll
    for (int off = 32; off; off >>= 1) {
        se += __shfl_down(se, off, 64);
        sx += __shfl_down(sx, off, 64);
    }
    if (lane == 0) { redA[w] = se; redB[w] = sx; }
    __syncthreads();
    if (i == 0) {
        float seT = redA[0] + redA[1], sxT = redB[0] + redB[1];
        float lse = m + __logf(seT);
        float nll = lse - xt;
        float smooth = lse - sxT * (1.f / 128.f);
        rowloss[n] = 0.9f * nll + 0.1f * smooth;
    }
}

__global__ __launch_bounds__(256) void loss_reduce_kernel(
    const float* __restrict__ rowloss, float* __restrict__ out)
{
    int tid = threadIdx.x;
    float sm = 0.f;
    for (int idx = tid; idx < N_; idx += 256) sm += rowloss[idx];
    #pragma unroll
    for (int off = 32; off; off >>= 1) sm += __shfl_down(sm, off, 64);
    __shared__ float red[4];
    int lane = tid & 63, w = tid >> 6;
    if (lane == 0) red[w] = sm;
    __syncthreads();
    if (tid == 0) out[0] = (red[0] + red[1] + red[2] + red[3]) * (1.f / (float)N_);
}

extern "C" void kernel_launch(void* const* d_in, const int* in_sizes, int n_in,
                              void* d_out, int out_size, void* d_ws, size_t ws_size,
                              hipStream_t stream)
{
    (void)in_sizes; (void)n_in; (void)out_size; (void)ws_size;
    const int* toks     = (const int*)d_in[0];
    const int* tgts     = (const int*)d_in[1];
    const float* emb    = (const float*)d_in[2];
    const float* qkv_w  = (const float*)d_in[3];
    const float* qkv_b  = (const float*)d_in[4];
    const float* aff1_w = (const float*)d_in[5];
    const float* aff1_b = (const float*)d_in[6];
    const float* aff2_w = (const float*)d_in[7];
    const float* aff2_b = (const float*)d_in[8];
    const float* ffn1_w = (const float*)d_in[9];
    const float* ffn1_b = (const float*)d_in[10];
    const float* ffn2_w = (const float*)d_in[11];
    const float* ffn2_b = (const float*)d_in[12];
    const float* ln1_s  = (const float*)d_in[13];
    const float* ln1_b  = (const float*)d_in[14];
    const float* ln2_s  = (const float*)d_in[15];
    const float* ln2_b  = (const float*)d_in[16];
    const float* head_w = (const float*)d_in[17];
    const float* head_b = (const float*)d_in[18];

    char* p = (char*)d_ws;
    auto carve = [&](size_t bytes) { char* r = p; p += (bytes + 255) & ~(size_t)255; return (void*)r; };
    unsigned short* wb_all  = (unsigned short*)carve((size_t)CVT_TOT * 2);
    unsigned short* wb_qkv  = wb_all;
    unsigned short* wb_aff1 = wb_qkv  + (size_t)CVT_N0;
    unsigned short* wb_aff2 = wb_aff1 + (size_t)CVT_N1;
    unsigned short* wb_ffn1 = wb_aff2 + (size_t)CVT_N1;
    unsigned short* wb_ffn2 = wb_ffn1 + (size_t)CVT_N1;
    unsigned short* wb_head = wb_ffn2 + (size_t)CVT_N1;
    float*          x_f     = (float*)carve((size_t)N_ * E_ * 4);
    unsigned short* x_b     = (unsigned short*)carve((size_t)N_ * E_ * 2);
    unsigned short* qkv_bf  = (unsigned short*)carve((size_t)N_ * E3_ * 2);
    unsigned short* att_b   = (unsigned short*)carve((size_t)N_ * E_ * 2);
    unsigned short* h_b     = (unsigned short*)carve((size_t)N_ * E_ * 2);
    float*          y_f     = (float*)carve((size_t)N_ * E_ * 4);
    float*          o1_f    = (float*)carve((size_t)N_ * E_ * 4);
    unsigned short* o1_b    = (unsigned short*)carve((size_t)N_ * E_ * 2);
    float*          logits  = (float*)carve((size_t)N_ * V_ * 4);
    float*          rowl    = (float*)carve((size_t)N_ * 4);
    float*          vtile   = (float*)carve((size_t)32 * 16 * 64 * 4);
    unsigned short* vt_g    = (unsigned short*)carve((size_t)32 * 64 * T_ * 2);  // 4 MB

    float* out_logits = (float*)d_out;
    float* out_loss   = out_logits + (size_t)N_ * V_;

    cvt_all_kernel<<<dim3(CVT_TOT / 1024), 256, 0, stream>>>(
        qkv_w, aff1_w, aff2_w, ffn1_w, ffn2_w, head_w, wb_all);

    embed_kernel<<<dim3((N_ * E_) / 256), 256, 0, stream>>>(toks, emb, x_f, x_b);

    for (int l = 0; l < L_; ++l) {
        gemm_mfma<0,0,1><<<dim3(E3_/64, N_/128), 256, 0, stream>>>(
            x_b, wb_qkv + (size_t)l * E3_ * E_, qkv_b + (size_t)l * E3_,
            nullptr, qkv_bf, N_, E3_, E_);
        vprep_kernel<<<dim3(32, 16), 256, 0, stream>>>(qkv_bf, vt_g, vtile);
        attn_mfma<<<dim3(32, 16), 256, 0, stream>>>(qkv_bf, vt_g, vtile, att_b);
        gemm_mfma<1,0,1><<<dim3(E_/64, N_/128), 256, 0, stream>>>(
            att_b, wb_aff1 + (size_t)l * E_ * E_, aff1_b + (size_t)l * E_,
            nullptr, h_b, N_, E_, E_);
        gemm_mfma<0,1,0><<<dim3(E_/64, N_/128), 256, 0, stream>>>(
            h_b, wb_aff2 + (size_t)l * E_ * E_, aff2_b + (size_t)l * E_,
            y_f, nullptr, N_, E_, E_);
        add_ln_kernel<<<dim3(N_/4), 256, 0, stream>>>(
            y_f, x_f, ln1_s + (size_t)l * E_, ln1_b + (size_t)l * E_, o1_f, o1_b);
        gemm_mfma<1,0,1><<<dim3(E_/64, N_/128), 256, 0, stream>>>(
            o1_b, wb_ffn1 + (size_t)l * E_ * E_, ffn1_b + (size_t)l * E_,
            nullptr, h_b, N_, E_, E_);
        gemm_mfma<0,1,0><<<dim3(E_/64, N_/128), 256, 0, stream>>>(
            h_b, wb_ffn2 + (size_t)l * E_ * E_, ffn2_b + (size_t)l * E_,
            y_f, nullptr, N_, E_, E_);
        add_ln_kernel<<<dim3(N_/4), 256, 0, stream>>>(
            o1_f, y_f, ln2_s + (size_t)l * E_, ln2_b + (size_t)l * E_, x_f, x_b);
    }

    gemm_mfma<0,1,0><<<dim3(V_/64, N_/128), 256, 0, stream>>>(
        x_b, wb_head, head_b, logits, nullptr, N_, V_, E_);
    loss_row_kernel<<<dim3(N_), 128, 0, stream>>>(logits, tgts, out_logits, rowl);
    loss_reduce_kernel<<<dim3(1), 256, 0, stream>>>(rowl, out_loss);
}

// Round 7
// 945.741 us; speedup vs baseline: 1.6142x; 1.6142x over previous
//
#include <hip/hip_runtime.h>

// 8-layer transformer LM forward. V=128, E=512, L=8, H=8, B=4, T=1024.
// Round 7: global_load_lds staging with SOURCE-PERMUTED addresses realizing the
// XOR-swizzled LDS layout (conflict-free ds_read_b128, zero staging VGPRs, no
// spill). GEMM BM=128/BN=64/BK=64. Attention stages Q/K/V the same way (V from
// pre-transposed vt_g); no register prefetch anywhere.

#define V_  128
#define E_  512
#define L_  8
#define H_  8
#define B_  4
#define T_  1024
#define N_  (B_*T_)    // 4096 tokens
#define DH_ 64
#define E3_ 1536

typedef __attribute__((ext_vector_type(8))) short   bf16x8;   // MFMA A/B frag
typedef __attribute__((ext_vector_type(4))) float   floatx4;  // MFMA C/D frag

// swizzled LDS offset (ushort units): 64-wide rows, 8-elem blocks XORed by row&7
#define SW(row,k8) (((row) << 6) + ((((k8) ^ ((row) & 7))) << 3))

__device__ __forceinline__ unsigned short f2bf(float f) {
    union { float f; unsigned int i; } v; v.f = f;
    unsigned int x = v.i;
    return (unsigned short)((x + 0x7fffu + ((x >> 16) & 1u)) >> 16);  // RNE
}
__device__ __forceinline__ float bf2f(unsigned short u) {
    union { unsigned int i; float f; } v; v.i = ((unsigned int)u) << 16; return v.f;
}
__device__ __forceinline__ void gload_lds16(const void* g, void* l) {
    __builtin_amdgcn_global_load_lds(
        (const __attribute__((address_space(1))) unsigned int*)g,
        (__attribute__((address_space(3))) unsigned int*)l, 16, 0, 0);
}

// ---------------- single-dispatch fp32 -> bf16 weight convert ----------------
#define CVT_N0 6291456   // qkv  L*1536*512
#define CVT_N1 2097152   // per-square L*512*512
#define CVT_TOT (CVT_N0 + 4*CVT_N1 + V_*E_)
__global__ void cvt_all_kernel(const float* __restrict__ s0, const float* __restrict__ s1,
                               const float* __restrict__ s2, const float* __restrict__ s3,
                               const float* __restrict__ s4, const float* __restrict__ s5,
                               unsigned short* __restrict__ dst) {
    long i = (long)(blockIdx.x * blockDim.x + threadIdx.x) * 4;
    if (i >= CVT_TOT) return;
    const float* src; long off;
    if      (i < CVT_N0)               { src = s0; off = i; }
    else if (i < CVT_N0 + CVT_N1)      { src = s1; off = i - CVT_N0; }
    else if (i < CVT_N0 + 2*CVT_N1)    { src = s2; off = i - CVT_N0 - CVT_N1; }
    else if (i < CVT_N0 + 3*CVT_N1)    { src = s3; off = i - CVT_N0 - 2L*CVT_N1; }
    else if (i < CVT_N0 + 4*CVT_N1)    { src = s4; off = i - CVT_N0 - 3L*CVT_N1; }
    else                               { src = s5; off = i - CVT_N0 - 4L*CVT_N1; }
    float4 v = *(const float4*)(src + off);
    ushort4 o; o.x = f2bf(v.x); o.y = f2bf(v.y); o.z = f2bf(v.z); o.w = f2bf(v.w);
    *(ushort4*)(dst + i) = o;
}

// ---------------- embedding: write fp32 + bf16 ----------------
__global__ void embed_kernel(const int* __restrict__ tok, const float* __restrict__ emb,
                             float* __restrict__ xf, unsigned short* __restrict__ xb) {
    int idx = blockIdx.x * blockDim.x + threadIdx.x;
    if (idx >= N_ * E_) return;
    int n = idx >> 9;
    int e = idx & (E_ - 1);
    float v = emb[tok[n] * E_ + e];
    xf[idx] = v; xb[idx] = f2bf(v);
}

// ---------------- MFMA GEMM: BM=128, BN=64, BK=64 ----------------
// global_load_lds with swizzle-permuted source chunks -> swizzled LDS layout,
// conflict-free frag reads, zero staging VGPRs.
template<int RELU, int WF, int WB>
__global__ __launch_bounds__(256) void gemm_mfma(
    const unsigned short* __restrict__ A, const unsigned short* __restrict__ W,
    const float* __restrict__ bias, float* __restrict__ Cf, unsigned short* __restrict__ Cb,
    int M, int Nout, int K)
{
    __shared__ unsigned short Asm[128 * 64];   // 16 KB, swizzled
    __shared__ unsigned short Bsm[64 * 64];    //  8 KB, swizzled
    int tid = threadIdx.x;
    int wv = tid >> 6, ln = tid & 63;
    int lquad = ln >> 4, lmod = ln & 15;
    int m0 = blockIdx.y * 128, n0 = blockIdx.x * 64;

    floatx4 acc[2][4] = {};

    for (int k0 = 0; k0 < K; k0 += 64) {
        __syncthreads();                     // prev chunk's readers done
        // A tile: 1024 chunks (16B each); lane fetches the chunk whose swizzled
        // home is its fixed LDS slot: k8_src = k8_dest ^ (row & 7)
        #pragma unroll
        for (int c = 0; c < 4; ++c) {
            int cc = tid + 256 * c;
            int r = cc >> 3, k8s = (cc & 7) ^ (r & 7);
            gload_lds16(A + (size_t)(m0 + r) * K + k0 + 8 * k8s, Asm + 2048 * c + 512 * wv);
        }
        #pragma unroll
        for (int c = 0; c < 2; ++c) {
            int cc = tid + 256 * c;
            int r = cc >> 3, k8s = (cc & 7) ^ (r & 7);
            gload_lds16(W + (size_t)(n0 + r) * K + k0 + 8 * k8s, Bsm + 2048 * c + 512 * wv);
        }
        __syncthreads();                     // drains vmcnt
        #pragma unroll
        for (int ks = 0; ks < 2; ++ks) {
            bf16x8 af[2], bfr[4];
            #pragma unroll
            for (int i = 0; i < 2; ++i)
                af[i] = *(const bf16x8*)&Asm[SW(32 * wv + 16 * i + lmod, ks * 4 + lquad)];
            #pragma unroll
            for (int j = 0; j < 4; ++j)
                bfr[j] = *(const bf16x8*)&Bsm[SW(16 * j + lmod, ks * 4 + lquad)];
            #pragma unroll
            for (int i = 0; i < 2; ++i)
                #pragma unroll
                for (int j = 0; j < 4; ++j)
                    acc[i][j] = __builtin_amdgcn_mfma_f32_16x16x32_bf16(af[i], bfr[j], acc[i][j], 0, 0, 0);
        }
    }
    #pragma unroll
    for (int i = 0; i < 2; ++i)
        #pragma unroll
        for (int j = 0; j < 4; ++j) {
            int n = n0 + 16 * j + lmod;
            float bj = bias[n];
            #pragma unroll
            for (int v = 0; v < 4; ++v) {
                int m = m0 + 32 * wv + 16 * i + 4 * lquad + v;
                float val = acc[i][j][v] + bj;
                if (RELU) val = fmaxf(val, 0.f);
                if (WF) Cf[(size_t)m * Nout + n] = val;
                if (WB) Cb[(size_t)m * Nout + n] = f2bf(val);
            }
        }
}

// ---------------- vprep: V transpose -> vt_g[bh][d][k] + tile sums ----------------
__global__ __launch_bounds__(256) void vprep_kernel(const unsigned short* __restrict__ qkv,
                                                    unsigned short* __restrict__ vt_g,
                                                    float* __restrict__ vtile) {
    int bh = blockIdx.x, kt = blockIdx.y;
    int b = bh >> 3, h = bh & 7;
    int tid = threadIdx.x, wv = tid >> 6, ln = tid & 63;
    int k0 = kt * 64;
    size_t base = (size_t)b * T_ * E3_ + h * 192 + 128;

    unsigned short vals[16];
    float s = 0.f;
    #pragma unroll
    for (int i = 0; i < 16; ++i) {
        vals[i] = qkv[base + (size_t)(k0 + wv * 16 + i) * E3_ + ln];
        s += bf2f(vals[i]);
    }
    #pragma unroll
    for (int hf = 0; hf < 2; ++hf) {
        union { unsigned short u[8]; uint4 v; } pk;
        #pragma unroll
        for (int i = 0; i < 8; ++i) pk.u[i] = vals[hf * 8 + i];
        *(uint4*)&vt_g[((size_t)(bh * 64 + ln)) * T_ + k0 + wv * 16 + hf * 8] = pk.v;
    }
    __shared__ float part[4][64];
    part[wv][ln] = s;
    __syncthreads();
    if (tid < 64)
        vtile[((size_t)bh * 16 + kt) * 64 + tid] =
            part[0][tid] + part[1][tid] + part[2][tid] + part[3][tid];
}

// ---------------- MFMA flash attention ----------------
// Grid (32 bh, 16 qt); 256 thr = 4 waves. Masked scores are ZERO (=> p = 1).
// All staging via global_load_lds with swizzle-permuted sources.
__global__ __launch_bounds__(256) void attn_mfma(const unsigned short* __restrict__ qkv,
                                                 const unsigned short* __restrict__ vt_g,
                                                 const float* __restrict__ vtile,
                                                 unsigned short* __restrict__ outb)
{
    __shared__ unsigned short Qs[64 * 64];  // [q][d] swizzled
    __shared__ unsigned short Ks[64 * 64];  // [k][d] swizzled
    __shared__ unsigned short Vs[64 * 64];  // [d][k] swizzled
    __shared__ unsigned short Ps[64 * 64];  // [q][k] swizzled

    int tid = threadIdx.x;
    int wv = tid >> 6, ln = tid & 63;
    int lquad = ln >> 4, lmod = ln & 15;
    int bh = blockIdx.x, qt = blockIdx.y;
    int b = bh >> 3, h = bh & 7;
    int q0 = qt * 64;
    const float scale = 0.125f;
    size_t base = (size_t)b * T_ * E3_ + h * 192;

    // stage Q (async; drained by the first in-loop barrier)
    #pragma unroll
    for (int c = 0; c < 2; ++c) {
        int cc = tid + 256 * c;
        int r = cc >> 3, k8s = (cc & 7) ^ (r & 7);
        gload_lds16(qkv + base + (size_t)(q0 + r) * E3_ + 8 * k8s, Qs + 2048 * c + 512 * wv);
    }

    float lrow[4] = {0.f, 0.f, 0.f, 0.f};
    floatx4 Oa[4] = {};

    for (int kt = 0; kt <= qt; ++kt) {
        int k0 = kt * 64;
        __syncthreads();   // prior Ks/Vs/Ps readers done (also orders vs Q loads)
        #pragma unroll
        for (int c = 0; c < 2; ++c) {
            int cc = tid + 256 * c;
            int r = cc >> 3, k8s = (cc & 7) ^ (r & 7);
            gload_lds16(qkv + base + (size_t)(k0 + r) * E3_ + 64 + 8 * k8s,
                        Ks + 2048 * c + 512 * wv);
            gload_lds16(vt_g + ((size_t)(bh * 64 + r)) * T_ + k0 + 8 * k8s,
                        Vs + 2048 * c + 512 * wv);
        }
        __syncthreads();   // drain

        // S strip = Q[16 rows]·K^T
        floatx4 sacc[4] = {};
        #pragma unroll
        for (int ks = 0; ks < 2; ++ks) {
            bf16x8 aq = *(const bf16x8*)&Qs[SW(16 * wv + lmod, ks * 4 + lquad)];
            #pragma unroll
            for (int j = 0; j < 4; ++j) {
                bf16x8 bk = *(const bf16x8*)&Ks[SW(16 * j + lmod, ks * 4 + lquad)];
                sacc[j] = __builtin_amdgcn_mfma_f32_16x16x32_bf16(aq, bk, sacc[j], 0, 0, 0);
            }
        }
        // p = exp(s*scale) (masked => exp(0)=1); per-lane partial sums only
        #pragma unroll
        for (int v = 0; v < 4; ++v) {
            int qg = q0 + 16 * wv + 4 * lquad + v;
            int row = 16 * wv + 4 * lquad + v;
            #pragma unroll
            for (int j = 0; j < 4; ++j) {
                int kg = k0 + 16 * j + lmod;
                float p = (kg <= qg) ? __expf(sacc[j][v] * scale) : 1.0f;
                lrow[v] += p;
                int col = 16 * j + lmod;
                Ps[SW(row, col >> 3) + (col & 7)] = f2bf(p);
            }
        }
        __syncthreads();   // Ps ready
        #pragma unroll
        for (int ks = 0; ks < 2; ++ks) {
            bf16x8 ap = *(const bf16x8*)&Ps[SW(16 * wv + lmod, ks * 4 + lquad)];
            #pragma unroll
            for (int f = 0; f < 4; ++f) {
                bf16x8 bv = *(const bf16x8*)&Vs[SW(16 * f + lmod, ks * 4 + lquad)];
                Oa[f] = __builtin_amdgcn_mfma_f32_16x16x32_bf16(ap, bv, Oa[f], 0, 0, 0);
            }
        }
    }

    // deferred row-sum reduction (16-lane groups share a row)
    #pragma unroll
    for (int v = 0; v < 4; ++v)
        #pragma unroll
        for (int msk = 1; msk < 16; msk <<= 1) lrow[v] += __shfl_xor(lrow[v], msk);

    // fully-masked suffix: p = 1 exactly; O += suffix V sums; l += count
    if (qt < 15) {
        float Km = (float)((15 - qt) * 64);
        #pragma unroll
        for (int v = 0; v < 4; ++v) lrow[v] += Km;
        #pragma unroll
        for (int f = 0; f < 4; ++f) {
            float sv = 0.f;
            for (int kt = qt + 1; kt < 16; ++kt)
                sv += vtile[((size_t)bh * 16 + kt) * 64 + 16 * f + lmod];
            #pragma unroll
            for (int v = 0; v < 4; ++v) Oa[f][v] += sv;
        }
    }

    #pragma unroll
    for (int f = 0; f < 4; ++f)
        #pragma unroll
        for (int v = 0; v < 4; ++v) {
            int q = q0 + 16 * wv + 4 * lquad + v;
            outb[(size_t)(b * T_ + q) * E_ + h * DH_ + 16 * f + lmod] = f2bf(Oa[f][v] / lrow[v]);
        }
}

// ---------------- residual add + LN: wave-per-row ----------------
__global__ __launch_bounds__(256) void add_ln_kernel(
    const float* __restrict__ a, const float* __restrict__ r,
    const float* __restrict__ s, const float* __restrict__ bpar,
    float* __restrict__ outF, unsigned short* __restrict__ outB)
{
    int tid = threadIdx.x, wv = tid >> 6, ln = tid & 63;
    int n = blockIdx.x * 4 + wv;
    int e = ln * 8;
    size_t base = (size_t)n * E_ + e;
    float4 a0 = *(const float4*)&a[base],     a1 = *(const float4*)&a[base + 4];
    float4 r0 = *(const float4*)&r[base],     r1 = *(const float4*)&r[base + 4];
    float v[8] = {a0.x + r0.x, a0.y + r0.y, a0.z + r0.z, a0.w + r0.w,
                  a1.x + r1.x, a1.y + r1.y, a1.z + r1.z, a1.w + r1.w};

    float sm = 0.f;
    #pragma unroll
    for (int i = 0; i < 8; ++i) sm += v[i];
    #pragma unroll
    for (int msk = 1; msk < 64; msk <<= 1) sm += __shfl_xor(sm, msk);
    float mu = sm * (1.f / 512.f);

    float ss = 0.f;
    #pragma unroll
    for (int i = 0; i < 8; ++i) { v[i] -= mu; ss += v[i] * v[i]; }
    #pragma unroll
    for (int msk = 1; msk < 64; msk <<= 1) ss += __shfl_xor(ss, msk);
    float rstd = rsqrtf(ss * (1.f / 512.f) + 1e-5f);

    float4 sc0 = *(const float4*)&s[e],    sc1 = *(const float4*)&s[e + 4];
    float4 bp0 = *(const float4*)&bpar[e], bp1 = *(const float4*)&bpar[e + 4];
    float o[8];
    o[0] = v[0] * rstd * sc0.x + bp0.x; o[1] = v[1] * rstd * sc0.y + bp0.y;
    o[2] = v[2] * rstd * sc0.z + bp0.z; o[3] = v[3] * rstd * sc0.w + bp0.w;
    o[4] = v[4] * rstd * sc1.x + bp1.x; o[5] = v[5] * rstd * sc1.y + bp1.y;
    o[6] = v[6] * rstd * sc1.z + bp1.z; o[7] = v[7] * rstd * sc1.w + bp1.w;
    *(float4*)&outF[base]     = make_float4(o[0], o[1], o[2], o[3]);
    *(float4*)&outF[base + 4] = make_float4(o[4], o[5], o[6], o[7]);
    union { unsigned short u[8]; uint4 q; } pk;
    #pragma unroll
    for (int i = 0; i < 8; ++i) pk.u[i] = f2bf(o[i]);
    *(uint4*)&outB[base] = pk.q;
}

// ---------------- per-row loss + fp32 logits out ----------------
__global__ __launch_bounds__(128) void loss_row_kernel(
    const float* __restrict__ logits, const int* __restrict__ tgt,
    float* __restrict__ out_logits, float* __restrict__ rowloss)
{
    int n = blockIdx.x, i = threadIdx.x;
    float x = logits[(size_t)n * V_ + i];
    out_logits[(size_t)n * V_ + i] = x;

    __shared__ float redA[2], redB[2];
    __shared__ float xt;
    int lane = i & 63, w = i >> 6;
    if (i == tgt[n]) xt = x;

    float m = x;
    #pragma unroll
    for (int off = 32; off; off >>= 1) m = fmaxf(m, __shfl_down(m, off, 64));
    if (lane == 0) redA[w] = m;
    __syncthreads();
    m = fmaxf(redA[0], redA[1]);
    __syncthreads();

    float ev = __expf(x - m);
    float se = ev, sx = x;
    #pragma unroll
    for (int off = 32; off; off >>= 1) {
        se += __shfl_down(se, off, 64);
        sx += __shfl_down(sx, off, 64);
    }
    if (lane == 0) { redA[w] = se; redB[w] = sx; }
    __syncthreads();
    if (i == 0) {
        float seT = redA[0] + redA[1], sxT = redB[0] + redB[1];
        float lse = m + __logf(seT);
        float nll = lse - xt;
        float smooth = lse - sxT * (1.f / 128.f);
        rowloss[n] = 0.9f * nll + 0.1f * smooth;
    }
}

__global__ __launch_bounds__(256) void loss_reduce_kernel(
    const float* __restrict__ rowloss, float* __restrict__ out)
{
    int tid = threadIdx.x;
    float sm = 0.f;
    for (int idx = tid; idx < N_; idx += 256) sm += rowloss[idx];
    #pragma unroll
    for (int off = 32; off; off >>= 1) sm += __shfl_down(sm, off, 64);
    __shared__ float red[4];
    int lane = tid & 63, w = tid >> 6;
    if (lane == 0) red[w] = sm;
    __syncthreads();
    if (tid == 0) out[0] = (red[0] + red[1] + red[2] + red[3]) * (1.f / (float)N_);
}

extern "C" void kernel_launch(void* const* d_in, const int* in_sizes, int n_in,
                              void* d_out, int out_size, void* d_ws, size_t ws_size,
                              hipStream_t stream)
{
    (void)in_sizes; (void)n_in; (void)out_size; (void)ws_size;
    const int* toks     = (const int*)d_in[0];
    const int* tgts     = (const int*)d_in[1];
    const float* emb    = (const float*)d_in[2];
    const float* qkv_w  = (const float*)d_in[3];
    const float* qkv_b  = (const float*)d_in[4];
    const float* aff1_w = (const float*)d_in[5];
    const float* aff1_b = (const float*)d_in[6];
    const float* aff2_w = (const float*)d_in[7];
    const float* aff2_b = (const float*)d_in[8];
    const float* ffn1_w = (const float*)d_in[9];
    const float* ffn1_b = (const float*)d_in[10];
    const float* ffn2_w = (const float*)d_in[11];
    const float* ffn2_b = (const float*)d_in[12];
    const float* ln1_s  = (const float*)d_in[13];
    const float* ln1_b  = (const float*)d_in[14];
    const float* ln2_s  = (const float*)d_in[15];
    const float* ln2_b  = (const float*)d_in[16];
    const float* head_w = (const float*)d_in[17];
    const float* head_b = (const float*)d_in[18];

    char* p = (char*)d_ws;
    auto carve = [&](size_t bytes) { char* r = p; p += (bytes + 255) & ~(size_t)255; return (void*)r; };
    unsigned short* wb_all  = (unsigned short*)carve((size_t)CVT_TOT * 2);
    unsigned short* wb_qkv  = wb_all;
    unsigned short* wb_aff1 = wb_qkv  + (size_t)CVT_N0;
    unsigned short* wb_aff2 = wb_aff1 + (size_t)CVT_N1;
    unsigned short* wb_ffn1 = wb_aff2 + (size_t)CVT_N1;
    unsigned short* wb_ffn2 = wb_ffn1 + (size_t)CVT_N1;
    unsigned short* wb_head = wb_ffn2 + (size_t)CVT_N1;
    float*          x_f     = (float*)carve((size_t)N_ * E_ * 4);
    unsigned short* x_b     = (unsigned short*)carve((size_t)N_ * E_ * 2);
    unsigned short* qkv_bf  = (unsigned short*)carve((size_t)N_ * E3_ * 2);
    unsigned short* att_b   = (unsigned short*)carve((size_t)N_ * E_ * 2);
    unsigned short* h_b     = (unsigned short*)carve((size_t)N_ * E_ * 2);
    float*          y_f     = (float*)carve((size_t)N_ * E_ * 4);
    float*          o1_f    = (float*)carve((size_t)N_ * E_ * 4);
    unsigned short* o1_b    = (unsigned short*)carve((size_t)N_ * E_ * 2);
    float*          logits  = (float*)carve((size_t)N_ * V_ * 4);
    float*          rowl    = (float*)carve((size_t)N_ * 4);
    float*          vtile   = (float*)carve((size_t)32 * 16 * 64 * 4);
    unsigned short* vt_g    = (unsigned short*)carve((size_t)32 * 64 * T_ * 2);  // 4 MB

    float* out_logits = (float*)d_out;
    float* out_loss   = out_logits + (size_t)N_ * V_;

    cvt_all_kernel<<<dim3(CVT_TOT / 1024), 256, 0, stream>>>(
        qkv_w, aff1_w, aff2_w, ffn1_w, ffn2_w, head_w, wb_all);

    embed_kernel<<<dim3((N_ * E_) / 256), 256, 0, stream>>>(toks, emb, x_f, x_b);

    for (int l = 0; l < L_; ++l) {
        gemm_mfma<0,0,1><<<dim3(E3_/64, N_/128), 256, 0, stream>>>(
            x_b, wb_qkv + (size_t)l * E3_ * E_, qkv_b + (size_t)l * E3_,
            nullptr, qkv_bf, N_, E3_, E_);
        vprep_kernel<<<dim3(32, 16), 256, 0, stream>>>(qkv_bf, vt_g, vtile);
        attn_mfma<<<dim3(32, 16), 256, 0, stream>>>(qkv_bf, vt_g, vtile, att_b);
        gemm_mfma<1,0,1><<<dim3(E_/64, N_/128), 256, 0, stream>>>(
            att_b, wb_aff1 + (size_t)l * E_ * E_, aff1_b + (size_t)l * E_,
            nullptr, h_b, N_, E_, E_);
        gemm_mfma<0,1,0><<<dim3(E_/64, N_/128), 256, 0, stream>>>(
            h_b, wb_aff2 + (size_t)l * E_ * E_, aff2_b + (size_t)l * E_,
            y_f, nullptr, N_, E_, E_);
        add_ln_kernel<<<dim3(N_/4), 256, 0, stream>>>(
            y_f, x_f, ln1_s + (size_t)l * E_, ln1_b + (size_t)l * E_, o1_f, o1_b);
        gemm_mfma<1,0,1><<<dim3(E_/64, N_/128), 256, 0, stream>>>(
            o1_b, wb_ffn1 + (size_t)l * E_ * E_, ffn1_b + (size_t)l * E_,
            nullptr, h_b, N_, E_, E_);
        gemm_mfma<0,1,0><<<dim3(E_/64, N_/128), 256, 0, stream>>>(
            h_b, wb_ffn2 + (size_t)l * E_ * E_, ffn2_b + (size_t)l * E_,
            y_f, nullptr, N_, E_, E_);
        add_ln_kernel<<<dim3(N_/4), 256, 0, stream>>>(
            o1_f, y_f, ln2_s + (size_t)l * E_, ln2_b + (size_t)l * E_, x_f, x_b);
    }

    gemm_mfma<0,1,0><<<dim3(V_/64, N_/128), 256, 0, stream>>>(
        x_b, wb_head, head_b, logits, nullptr, N_, V_, E_);
    loss_row_kernel<<<dim3(N_), 128, 0, stream>>>(logits, tgts, out_logits, rowl);
    loss_reduce_kernel<<<dim3(1), 256, 0, stream>>>(rowl, out_loss);
}